// Round 5
// baseline (96.515 us; speedup 1.0000x reference)
//
#include <hip/hip_runtime.h>

// VQ color lookup, round 15: revert to R13 numerics + 2-pair tree select.
// R14 post-mortem: dropping hz from the score flipped >=1 argmin (absmax
// 0.30) -> this dataset has pixels with top-2 gaps inside fp32 noise; only
// R13's exact formula (fma chain seeded with hz, trailing +cw) is known to
// match numpy on all 524k px (absmax 0.0). Reverted bitwise.
// New lever: selects are EXACT ops -- restructure without numeric risk.
// Group 2 pairs (4 entries, = one s_load_dwordx16) per select:
//   mn = min3(min3(best, r0.x, r0.y), r1.x, r1.y); cmp; cndmask
// = 8cy/px per 2 pairs vs 12cy -> inner step 176 -> 160cy (-9%).
// Index at group granularity; resolve recomputes the 4 entry scores of the
// winning group with scalar fmaf chains (bitwise == pk lanes: v_pk_fma
// lane = IEEE fmaf, v_pk_add lane = scalar add) and picks the FIRST entry
// == best -> numpy first-index preserved. Group-vs-group tie: strict <
// keeps earlier group. SMEM delivery unchanged: s_load_dwordx16 (2 Pairs),
// A/B double-buffer, one SMEM op outstanding per lgkmcnt(0) fence, fence
// tied "+s" through the buffer.

#define KPAL 512
#define HW   65536            // 256*256
#define CHW  (3 * HW)
#define NPIX (8 * HW)         // 524288 pixels
#define NELEM (NPIX * 3)      // 1572864 output color elements
#define PPT   4               // pixels per thread (64 lanes * 4 = 256 px/block)
#define NWAVE 4
#define PAIRS_PER_WAVE (KPAL / 2 / NWAVE)   // 64
#define GROUPS_PER_WAVE (PAIRS_PER_WAVE / 2) // 32 (2 pairs = 4 entries each)

typedef float f2   __attribute__((ext_vector_type(2)));
typedef float f16v __attribute__((ext_vector_type(16)));

struct __align__(32) Pair {   // palette entries 2j (lo half) and 2j+1 (hi)
    f2 x, y, z, w;            // x,y,z = NEGATED color; w = 0.5 * ||t||^2
};

__device__ Pair g_pairs[KPAL / 2];          // 8 KB static device memory

// Pack the negated pair table; zero the loss accumulator.
__global__ void prep_kernel(const float* __restrict__ table,
                            float* __restrict__ loss)
{
    const int j = threadIdx.x;            // 0..255
    if (j == 0) *loss = 0.0f;
    const float a0 = table[6 * j + 0], a1 = table[6 * j + 1], a2 = table[6 * j + 2];
    const float b0 = table[6 * j + 3], b1 = table[6 * j + 4], b2 = table[6 * j + 5];
    float aw, bw;
    {
#pragma clang fp contract(off)
        aw = a0 * a0 + a1 * a1 + a2 * a2;
        bw = b0 * b0 + b1 * b1 + b2 * b2;
    }
    Pair p;
    p.x = (f2){-a0, -b0};
    p.y = (f2){-a1, -b1};
    p.z = (f2){-a2, -b2};
    p.w = (f2){0.5f * aw, 0.5f * bw};     // exact
    g_pairs[j] = p;
}

// 4 pixels x 1 palette pair (R13-exact numerics):
//   d = fma(nz, z2, fma(ny, z1, fma(nx, z0, hz))) + cw
// nx,ny,nz,cw are SGPR pairs (one per instr -> constant-bus legal).
// ZA=(z0,z1), ZB=(z2,hz); op_sel broadcasts the pixel component and hz.
static __device__ __forceinline__ void quad_dist_s(
    f2 nx, f2 ny, f2 nz, f2 cw,
    f2 A0, f2 B0, f2 A1, f2 B1, f2 A2, f2 B2, f2 A3, f2 B3,
    f2& r0, f2& r1, f2& r2, f2& r3)
{
    f2 d0, d1, d2, d3;
    asm("v_pk_fma_f32 %[d0], %[nx], %[A0], %[B0] op_sel:[0,0,1] op_sel_hi:[1,0,1]\n\t"
        "v_pk_fma_f32 %[d1], %[nx], %[A1], %[B1] op_sel:[0,0,1] op_sel_hi:[1,0,1]\n\t"
        "v_pk_fma_f32 %[d2], %[nx], %[A2], %[B2] op_sel:[0,0,1] op_sel_hi:[1,0,1]\n\t"
        "v_pk_fma_f32 %[d3], %[nx], %[A3], %[B3] op_sel:[0,0,1] op_sel_hi:[1,0,1]\n\t"
        "v_pk_fma_f32 %[d0], %[ny], %[A0], %[d0] op_sel:[0,1,0] op_sel_hi:[1,1,1]\n\t"
        "v_pk_fma_f32 %[d1], %[ny], %[A1], %[d1] op_sel:[0,1,0] op_sel_hi:[1,1,1]\n\t"
        "v_pk_fma_f32 %[d2], %[ny], %[A2], %[d2] op_sel:[0,1,0] op_sel_hi:[1,1,1]\n\t"
        "v_pk_fma_f32 %[d3], %[ny], %[A3], %[d3] op_sel:[0,1,0] op_sel_hi:[1,1,1]\n\t"
        "v_pk_fma_f32 %[d0], %[nz], %[B0], %[d0] op_sel:[0,0,0] op_sel_hi:[1,0,1]\n\t"
        "v_pk_fma_f32 %[d1], %[nz], %[B1], %[d1] op_sel:[0,0,0] op_sel_hi:[1,0,1]\n\t"
        "v_pk_fma_f32 %[d2], %[nz], %[B2], %[d2] op_sel:[0,0,0] op_sel_hi:[1,0,1]\n\t"
        "v_pk_fma_f32 %[d3], %[nz], %[B3], %[d3] op_sel:[0,0,0] op_sel_hi:[1,0,1]\n\t"
        "v_pk_add_f32 %[d0], %[d0], %[cw]\n\t"
        "v_pk_add_f32 %[d1], %[d1], %[cw]\n\t"
        "v_pk_add_f32 %[d2], %[d2], %[cw]\n\t"
        "v_pk_add_f32 %[d3], %[d3], %[cw]"
        : [d0] "=&v"(d0), [d1] "=&v"(d1), [d2] "=&v"(d2), [d3] "=&v"(d3)
        : [A0] "v"(A0), [B0] "v"(B0), [A1] "v"(A1), [B1] "v"(B1),
          [A2] "v"(A2), [B2] "v"(B2), [A3] "v"(A3), [B3] "v"(B3),
          [nx] "s"(nx), [ny] "s"(ny), [nz] "s"(nz), [cw] "s"(cw));
    r0 = d0; r1 = d1; r2 = d2; r3 = d3;
}

// One s_load_dwordx16 (two Pairs) into an SGPR 16-tuple; fence ties the
// wait through the destination so no consumer can be scheduled before it.
#define SLOAD2(dst, off) \
    asm volatile("s_load_dwordx16 %0, %1, %2" : "=s"(dst) : "s"(pairs), "s"(off))
#define SFENCE(dst) \
    asm volatile("s_waitcnt lgkmcnt(0)" : "+s"(dst))

__global__ __launch_bounds__(256, 4)
void vq_kernel(const float* __restrict__ z,
               const float* __restrict__ table,
               float* __restrict__ out,
               float* __restrict__ loss)
{
    __shared__ float cb_best[NWAVE][256];   // 4 KB
    __shared__ int   cb_bi[NWAVE][256];     // 4 KB
    __shared__ float wsum[NWAVE];
    const Pair* pairs = g_pairs;
    const int t = threadIdx.x;
    const int w = t >> 6, lane = t & 63;
    const int wu = __builtin_amdgcn_readfirstlane(w);   // wave-uniform SGPR

    // Block covers 256 consecutive pixels; all 4 waves process the same px.
    const int blockbase = blockIdx.x * 256;
    const int b  = blockbase >> 16;           // blocks never straddle batch
    const int p0 = blockbase & (HW - 1);
    const int base0 = b * CHW + p0 + lane;    // pixel i at base0 + 64*i

    f2 ZA[PPT], ZB[PPT];                      // (z0,z1), (z2, 0.5*||z||^2)
#pragma unroll
    for (int i = 0; i < PPT; ++i) {
        const int base = base0 + 64 * i;
        const float z0 = z[base];
        const float z1 = z[base + HW];
        const float z2 = z[base + 2 * HW];
        float zs;
        {
#pragma clang fp contract(off)
            zs = z0 * z0 + z1 * z1 + z2 * z2;
        }
        ZA[i] = (f2){z0, z1};
        ZB[i] = (f2){z2, 0.5f * zs};          // exact halve
    }

    float best[PPT];
    int   bg[PPT];                            // global GROUP index (4 entries)
#pragma unroll
    for (int i = 0; i < PPT; ++i) { best[i] = 3.4e38f; bg[i] = wu * GROUPS_PER_WAVE; }

    // Wave w scans its palette quarter; one x16 load = one 4-entry group.
    const unsigned wbase = (unsigned)(wu * PAIRS_PER_WAVE) * 32u;

    // One group = 2 pairs from one x16 buffer. Tree select (exact compares):
    // mn = min3(min3(best, ra.x, ra.y), rb.x, rb.y); strict < keeps the
    // earlier group on ties -> numpy first-index at group level.
#define GROUP_STEP(V, G)                                                     \
    do {                                                                     \
        const f2 nx0 = (f2){(V)[0], (V)[1]};                                 \
        const f2 ny0 = (f2){(V)[2], (V)[3]};                                 \
        const f2 nz0 = (f2){(V)[4], (V)[5]};                                 \
        const f2 cw0 = (f2){(V)[6], (V)[7]};                                 \
        const f2 nx1 = (f2){(V)[8], (V)[9]};                                 \
        const f2 ny1 = (f2){(V)[10], (V)[11]};                               \
        const f2 nz1 = (f2){(V)[12], (V)[13]};                               \
        const f2 cw1 = (f2){(V)[14], (V)[15]};                               \
        f2 ra[PPT], rb[PPT];                                                 \
        quad_dist_s(nx0, ny0, nz0, cw0,                                      \
                    ZA[0], ZB[0], ZA[1], ZB[1], ZA[2], ZB[2], ZA[3], ZB[3],  \
                    ra[0], ra[1], ra[2], ra[3]);                             \
        quad_dist_s(nx1, ny1, nz1, cw1,                                      \
                    ZA[0], ZB[0], ZA[1], ZB[1], ZA[2], ZB[2], ZA[3], ZB[3],  \
                    rb[0], rb[1], rb[2], rb[3]);                             \
        const int gv = (G);                                                  \
        _Pragma("unroll")                                                    \
        for (int i = 0; i < PPT; ++i) {                                      \
            const float m1 = fminf(fminf(best[i], ra[i].x), ra[i].y);        \
            const float mn = fminf(fminf(m1, rb[i].x), rb[i].y);             \
            const bool imp = mn < best[i];                                   \
            bg[i] = imp ? gv : bg[i];                                        \
            best[i] = mn;                                                    \
        }                                                                    \
    } while (0)

    {
        f16v A, B;
        SLOAD2(A, wbase);                                 // group 0 (pairs 0,1)
#pragma unroll 1
        for (int c = 0; c < PAIRS_PER_WAVE; c += 4) {
            SFENCE(A);                                    // only A outstanding
            const unsigned offB = wbase + (unsigned)(c + 2) * 32u;
            SLOAD2(B, offB);                              // hides under group A
            GROUP_STEP(A, wu * GROUPS_PER_WAVE + (c >> 1));
            SFENCE(B);                                    // only B outstanding
            if (c + 4 < PAIRS_PER_WAVE) {
                const unsigned offA = wbase + (unsigned)(c + 4) * 32u;
                SLOAD2(A, offA);                          // hides under group B
            }
            GROUP_STEP(B, wu * GROUPS_PER_WAVE + (c >> 1) + 1);
        }
    }
#undef GROUP_STEP

    // Resolve the winning entry within the winning 4-entry group: recompute
    // all 4 scores with scalar chains that replicate the pk lanes BITWISE
    // (v_pk_fma lane == fmaf, v_pk_add lane == scalar add); first == best
    // -> numpy first-index within the group.
#pragma unroll
    for (int i = 0; i < PPT; ++i) {
        const int g = bg[i];
        const Pair ca = pairs[2 * g];         // per-lane gather, L1-hit (8 KB)
        const Pair cb2 = pairs[2 * g + 1];
        float s0, s1, s2, s3;
        {
#pragma clang fp contract(off)
            float m;
            m = fmaf(ca.x.x, ZA[i].x, ZB[i].y);
            m = fmaf(ca.y.x, ZA[i].y, m);
            m = fmaf(ca.z.x, ZB[i].x, m);
            s0 = m + ca.w.x;
            m = fmaf(ca.x.y, ZA[i].x, ZB[i].y);
            m = fmaf(ca.y.y, ZA[i].y, m);
            m = fmaf(ca.z.y, ZB[i].x, m);
            s1 = m + ca.w.y;
            m = fmaf(cb2.x.x, ZA[i].x, ZB[i].y);
            m = fmaf(cb2.y.x, ZA[i].y, m);
            m = fmaf(cb2.z.x, ZB[i].x, m);
            s2 = m + cb2.w.x;
            m = fmaf(cb2.x.y, ZA[i].x, ZB[i].y);
            m = fmaf(cb2.y.y, ZA[i].y, m);
            m = fmaf(cb2.z.y, ZB[i].x, m);
            s3 = m + cb2.w.y;
        }
        const int m4 = (s0 == best[i]) ? 0 : (s1 == best[i]) ? 1
                     : (s2 == best[i]) ? 2 : 3;
        cb_best[w][lane + 64 * i] = best[i];
        cb_bi[w][lane + 64 * i]   = 4 * g + m4;
    }
    __syncthreads();

    // Combine quarters (ordered strict < => numpy first-index), write, loss.
    // px p = t was scanned by THIS thread at slot i == w: reuse regs, no z re-read.
    f2 zA = ZA[0], zB = ZB[0];
    if (w == 1)      { zA = ZA[1]; zB = ZB[1]; }
    else if (w == 2) { zA = ZA[2]; zB = ZB[2]; }
    else if (w == 3) { zA = ZA[3]; zB = ZB[3]; }

    float lsum = 0.0f;
    {
        const int p = t;                      // 0..255 within block
        float bb = cb_best[0][p];
        int   kk = cb_bi[0][p];
#pragma unroll
        for (int ww = 1; ww < NWAVE; ++ww) {
            const float d  = cb_best[ww][p];
            const int   k2 = cb_bi[ww][p];
            if (d < bb) { bb = d; kk = k2; }
        }
        const int base = b * CHW + p0 + p;
        const float c0 = table[3 * kk + 0];
        const float c1 = table[3 * kk + 1];
        const float c2 = table[3 * kk + 2];
        out[base]          = c0;
        out[base + HW]     = c1;
        out[base + 2 * HW] = c2;
        const float e0 = c0 - zA.x, e1 = c1 - zA.y, e2 = c2 - zB.x;
        lsum = e0 * e0 + e1 * e1 + e2 * e2;
    }

    for (int off = 32; off > 0; off >>= 1)
        lsum += __shfl_down(lsum, off);

    if ((t & 63) == 0) wsum[w] = lsum;
    __syncthreads();
    if (t == 0) {
        const float s = wsum[0] + wsum[1] + wsum[2] + wsum[3];
        atomicAdd(loss, s * (11.0f / (float)NELEM));
    }
}

extern "C" void kernel_launch(void* const* d_in, const int* in_sizes, int n_in,
                              void* d_out, int out_size, void* d_ws, size_t ws_size,
                              hipStream_t stream)
{
    const float* z     = (const float*)d_in[0];
    const float* table = (const float*)d_in[1];
    float* out  = (float*)d_out;
    float* loss = out + NELEM;

    prep_kernel<<<1, 256, 0, stream>>>(table, loss);
    vq_kernel<<<NPIX / 256, 256, 0, stream>>>(z, table, out, loss);
}

// Round 6
// 93.489 us; speedup vs baseline: 1.0324x; 1.0324x over previous
//
#include <hip/hip_runtime.h>

// VQ color lookup, round 16: unlock occupancy + halve SMEM fence rate.
// R15 post-mortem: tree select cut issue work 27% but dur flat at ~41us,
// VALUBusy 70->55% -> NOT issue-bound. Occupancy pinned at ~42-47% (~3.5
// waves/SIMD) since R10 across different LDS/VGPR configs; common factor is
// __launch_bounds__(256,4) -> amdgpu-waves-per-eu=4 acting as a cap (4/8 =
// 50% ~ measured). VGPR=32 allows 8 waves/SIMD. Fix 1: (256,8) (VGPR cap
// 64, we use 32). Fix 2: halve fence rate -- 4 SMEM buffers (A1,A2,B1,B2),
// loads issued in pairs, ONE lgkmcnt(0) per 2 group-steps (~320-cyc cover);
// at each fence exactly the 2 waited loads are outstanding (SMEM may
// complete OOO -> only a full drain is safe; deep rotation with counted
// lgkm is NOT). Numerics bitwise-identical to R15 (absmax 0.0): R13 score
// formula (fma chain seeded with hz, trailing +cw), exact tree select,
// bitwise scalar resolve, strict-< first-index combine.

#define KPAL 512
#define HW   65536            // 256*256
#define CHW  (3 * HW)
#define NPIX (8 * HW)         // 524288 pixels
#define NELEM (NPIX * 3)      // 1572864 output color elements
#define PPT   4               // pixels per thread (64 lanes * 4 = 256 px/block)
#define NWAVE 4
#define PAIRS_PER_WAVE (KPAL / 2 / NWAVE)   // 64
#define GROUPS_PER_WAVE (PAIRS_PER_WAVE / 2) // 32 (2 pairs = 4 entries each)

typedef float f2   __attribute__((ext_vector_type(2)));
typedef float f16v __attribute__((ext_vector_type(16)));

struct __align__(32) Pair {   // palette entries 2j (lo half) and 2j+1 (hi)
    f2 x, y, z, w;            // x,y,z = NEGATED color; w = 0.5 * ||t||^2
};

__device__ Pair g_pairs[KPAL / 2];          // 8 KB static device memory

// Pack the negated pair table; zero the loss accumulator.
__global__ void prep_kernel(const float* __restrict__ table,
                            float* __restrict__ loss)
{
    const int j = threadIdx.x;            // 0..255
    if (j == 0) *loss = 0.0f;
    const float a0 = table[6 * j + 0], a1 = table[6 * j + 1], a2 = table[6 * j + 2];
    const float b0 = table[6 * j + 3], b1 = table[6 * j + 4], b2 = table[6 * j + 5];
    float aw, bw;
    {
#pragma clang fp contract(off)
        aw = a0 * a0 + a1 * a1 + a2 * a2;
        bw = b0 * b0 + b1 * b1 + b2 * b2;
    }
    Pair p;
    p.x = (f2){-a0, -b0};
    p.y = (f2){-a1, -b1};
    p.z = (f2){-a2, -b2};
    p.w = (f2){0.5f * aw, 0.5f * bw};     // exact
    g_pairs[j] = p;
}

// 4 pixels x 1 palette pair (R13-exact numerics):
//   d = fma(nz, z2, fma(ny, z1, fma(nx, z0, hz))) + cw
// nx,ny,nz,cw are SGPR pairs (one per instr -> constant-bus legal).
// ZA=(z0,z1), ZB=(z2,hz); op_sel broadcasts the pixel component and hz.
static __device__ __forceinline__ void quad_dist_s(
    f2 nx, f2 ny, f2 nz, f2 cw,
    f2 A0, f2 B0, f2 A1, f2 B1, f2 A2, f2 B2, f2 A3, f2 B3,
    f2& r0, f2& r1, f2& r2, f2& r3)
{
    f2 d0, d1, d2, d3;
    asm("v_pk_fma_f32 %[d0], %[nx], %[A0], %[B0] op_sel:[0,0,1] op_sel_hi:[1,0,1]\n\t"
        "v_pk_fma_f32 %[d1], %[nx], %[A1], %[B1] op_sel:[0,0,1] op_sel_hi:[1,0,1]\n\t"
        "v_pk_fma_f32 %[d2], %[nx], %[A2], %[B2] op_sel:[0,0,1] op_sel_hi:[1,0,1]\n\t"
        "v_pk_fma_f32 %[d3], %[nx], %[A3], %[B3] op_sel:[0,0,1] op_sel_hi:[1,0,1]\n\t"
        "v_pk_fma_f32 %[d0], %[ny], %[A0], %[d0] op_sel:[0,1,0] op_sel_hi:[1,1,1]\n\t"
        "v_pk_fma_f32 %[d1], %[ny], %[A1], %[d1] op_sel:[0,1,0] op_sel_hi:[1,1,1]\n\t"
        "v_pk_fma_f32 %[d2], %[ny], %[A2], %[d2] op_sel:[0,1,0] op_sel_hi:[1,1,1]\n\t"
        "v_pk_fma_f32 %[d3], %[ny], %[A3], %[d3] op_sel:[0,1,0] op_sel_hi:[1,1,1]\n\t"
        "v_pk_fma_f32 %[d0], %[nz], %[B0], %[d0] op_sel:[0,0,0] op_sel_hi:[1,0,1]\n\t"
        "v_pk_fma_f32 %[d1], %[nz], %[B1], %[d1] op_sel:[0,0,0] op_sel_hi:[1,0,1]\n\t"
        "v_pk_fma_f32 %[d2], %[nz], %[B2], %[d2] op_sel:[0,0,0] op_sel_hi:[1,0,1]\n\t"
        "v_pk_fma_f32 %[d3], %[nz], %[B3], %[d3] op_sel:[0,0,0] op_sel_hi:[1,0,1]\n\t"
        "v_pk_add_f32 %[d0], %[d0], %[cw]\n\t"
        "v_pk_add_f32 %[d1], %[d1], %[cw]\n\t"
        "v_pk_add_f32 %[d2], %[d2], %[cw]\n\t"
        "v_pk_add_f32 %[d3], %[d3], %[cw]"
        : [d0] "=&v"(d0), [d1] "=&v"(d1), [d2] "=&v"(d2), [d3] "=&v"(d3)
        : [A0] "v"(A0), [B0] "v"(B0), [A1] "v"(A1), [B1] "v"(B1),
          [A2] "v"(A2), [B2] "v"(B2), [A3] "v"(A3), [B3] "v"(B3),
          [nx] "s"(nx), [ny] "s"(ny), [nz] "s"(nz), [cw] "s"(cw));
    r0 = d0; r1 = d1; r2 = d2; r3 = d3;
}

// One s_load_dwordx16 (two Pairs = one 4-entry group) into an SGPR 16-tuple.
#define SLOAD2(dst, off) \
    asm volatile("s_load_dwordx16 %0, %1, %2" : "=s"(dst) : "s"(pairs), "s"(off))
// Drain SMEM; tie both waited buffers so extraction can't hoist past it.
#define SFENCE2(d1, d2) \
    asm volatile("s_waitcnt lgkmcnt(0)" : "+s"(d1), "+s"(d2))

__global__ __launch_bounds__(256, 8)
void vq_kernel(const float* __restrict__ z,
               const float* __restrict__ table,
               float* __restrict__ out,
               float* __restrict__ loss)
{
    __shared__ float cb_best[NWAVE][256];   // 4 KB
    __shared__ int   cb_bi[NWAVE][256];     // 4 KB
    __shared__ float wsum[NWAVE];
    const Pair* pairs = g_pairs;
    const int t = threadIdx.x;
    const int w = t >> 6, lane = t & 63;
    const int wu = __builtin_amdgcn_readfirstlane(w);   // wave-uniform SGPR

    // Block covers 256 consecutive pixels; all 4 waves process the same px.
    const int blockbase = blockIdx.x * 256;
    const int b  = blockbase >> 16;           // blocks never straddle batch
    const int p0 = blockbase & (HW - 1);
    const int base0 = b * CHW + p0 + lane;    // pixel i at base0 + 64*i

    f2 ZA[PPT], ZB[PPT];                      // (z0,z1), (z2, 0.5*||z||^2)
#pragma unroll
    for (int i = 0; i < PPT; ++i) {
        const int base = base0 + 64 * i;
        const float z0 = z[base];
        const float z1 = z[base + HW];
        const float z2 = z[base + 2 * HW];
        float zs;
        {
#pragma clang fp contract(off)
            zs = z0 * z0 + z1 * z1 + z2 * z2;
        }
        ZA[i] = (f2){z0, z1};
        ZB[i] = (f2){z2, 0.5f * zs};          // exact halve
    }

    float best[PPT];
    int   bg[PPT];                            // global GROUP index (4 entries)
#pragma unroll
    for (int i = 0; i < PPT; ++i) { best[i] = 3.4e38f; bg[i] = wu * GROUPS_PER_WAVE; }

    // Wave w scans its palette quarter; one x16 load = one 4-entry group.
    const unsigned wbase = (unsigned)(wu * PAIRS_PER_WAVE) * 32u;

    // One group = 2 pairs from one x16 buffer. Tree select (exact compares):
    // mn = min3(min3(best, ra.x, ra.y), rb.x, rb.y); strict < keeps the
    // earlier group on ties -> numpy first-index at group level.
#define GROUP_STEP(V, G)                                                     \
    do {                                                                     \
        const f2 nx0 = (f2){(V)[0], (V)[1]};                                 \
        const f2 ny0 = (f2){(V)[2], (V)[3]};                                 \
        const f2 nz0 = (f2){(V)[4], (V)[5]};                                 \
        const f2 cw0 = (f2){(V)[6], (V)[7]};                                 \
        const f2 nx1 = (f2){(V)[8], (V)[9]};                                 \
        const f2 ny1 = (f2){(V)[10], (V)[11]};                               \
        const f2 nz1 = (f2){(V)[12], (V)[13]};                               \
        const f2 cw1 = (f2){(V)[14], (V)[15]};                               \
        f2 ra[PPT], rb[PPT];                                                 \
        quad_dist_s(nx0, ny0, nz0, cw0,                                      \
                    ZA[0], ZB[0], ZA[1], ZB[1], ZA[2], ZB[2], ZA[3], ZB[3],  \
                    ra[0], ra[1], ra[2], ra[3]);                             \
        quad_dist_s(nx1, ny1, nz1, cw1,                                      \
                    ZA[0], ZB[0], ZA[1], ZB[1], ZA[2], ZB[2], ZA[3], ZB[3],  \
                    rb[0], rb[1], rb[2], rb[3]);                             \
        const int gv = (G);                                                  \
        _Pragma("unroll")                                                    \
        for (int i = 0; i < PPT; ++i) {                                      \
            const float m1 = fminf(fminf(best[i], ra[i].x), ra[i].y);        \
            const float mn = fminf(fminf(m1, rb[i].x), rb[i].y);             \
            const bool imp = mn < best[i];                                   \
            bg[i] = imp ? gv : bg[i];                                        \
            best[i] = mn;                                                    \
        }                                                                    \
    } while (0)

    {
        f16v A1, A2, B1, B2;
        SLOAD2(A1, wbase);                                // groups 0,1
        SLOAD2(A2, wbase + 64u);
#pragma unroll 1
        for (int c = 0; c < PAIRS_PER_WAVE; c += 8) {     // 8 pairs = 4 groups
            const int g0 = wu * GROUPS_PER_WAVE + (c >> 1);
            SFENCE2(A1, A2);                              // only A1,A2 were outstanding
            SLOAD2(B1, wbase + (unsigned)(c + 4) * 32u);  // hide under 2 group-steps
            SLOAD2(B2, wbase + (unsigned)(c + 6) * 32u);
            GROUP_STEP(A1, g0);
            GROUP_STEP(A2, g0 + 1);
            SFENCE2(B1, B2);                              // only B1,B2 outstanding
            if (c + 8 < PAIRS_PER_WAVE) {
                SLOAD2(A1, wbase + (unsigned)(c + 8) * 32u);
                SLOAD2(A2, wbase + (unsigned)(c + 10) * 32u);
            }
            GROUP_STEP(B1, g0 + 2);
            GROUP_STEP(B2, g0 + 3);
        }
    }
#undef GROUP_STEP

    // Resolve the winning entry within the winning 4-entry group: recompute
    // all 4 scores with scalar chains that replicate the pk lanes BITWISE
    // (v_pk_fma lane == fmaf, v_pk_add lane == scalar add); first == best
    // -> numpy first-index within the group.
#pragma unroll
    for (int i = 0; i < PPT; ++i) {
        const int g = bg[i];
        const Pair ca = pairs[2 * g];         // per-lane gather, L1-hit (8 KB)
        const Pair cb2 = pairs[2 * g + 1];
        float s0, s1, s2, s3;
        {
#pragma clang fp contract(off)
            float m;
            m = fmaf(ca.x.x, ZA[i].x, ZB[i].y);
            m = fmaf(ca.y.x, ZA[i].y, m);
            m = fmaf(ca.z.x, ZB[i].x, m);
            s0 = m + ca.w.x;
            m = fmaf(ca.x.y, ZA[i].x, ZB[i].y);
            m = fmaf(ca.y.y, ZA[i].y, m);
            m = fmaf(ca.z.y, ZB[i].x, m);
            s1 = m + ca.w.y;
            m = fmaf(cb2.x.x, ZA[i].x, ZB[i].y);
            m = fmaf(cb2.y.x, ZA[i].y, m);
            m = fmaf(cb2.z.x, ZB[i].x, m);
            s2 = m + cb2.w.x;
            m = fmaf(cb2.x.y, ZA[i].x, ZB[i].y);
            m = fmaf(cb2.y.y, ZA[i].y, m);
            m = fmaf(cb2.z.y, ZB[i].x, m);
            s3 = m + cb2.w.y;
        }
        const int m4 = (s0 == best[i]) ? 0 : (s1 == best[i]) ? 1
                     : (s2 == best[i]) ? 2 : 3;
        cb_best[w][lane + 64 * i] = best[i];
        cb_bi[w][lane + 64 * i]   = 4 * g + m4;
    }
    __syncthreads();

    // Combine quarters (ordered strict < => numpy first-index), write, loss.
    // px p = t was scanned by THIS thread at slot i == w: reuse regs, no z re-read.
    f2 zA = ZA[0], zB = ZB[0];
    if (w == 1)      { zA = ZA[1]; zB = ZB[1]; }
    else if (w == 2) { zA = ZA[2]; zB = ZB[2]; }
    else if (w == 3) { zA = ZA[3]; zB = ZB[3]; }

    float lsum = 0.0f;
    {
        const int p = t;                      // 0..255 within block
        float bb = cb_best[0][p];
        int   kk = cb_bi[0][p];
#pragma unroll
        for (int ww = 1; ww < NWAVE; ++ww) {
            const float d  = cb_best[ww][p];
            const int   k2 = cb_bi[ww][p];
            if (d < bb) { bb = d; kk = k2; }
        }
        const int base = b * CHW + p0 + p;
        const float c0 = table[3 * kk + 0];
        const float c1 = table[3 * kk + 1];
        const float c2 = table[3 * kk + 2];
        out[base]          = c0;
        out[base + HW]     = c1;
        out[base + 2 * HW] = c2;
        const float e0 = c0 - zA.x, e1 = c1 - zA.y, e2 = c2 - zB.x;
        lsum = e0 * e0 + e1 * e1 + e2 * e2;
    }

    for (int off = 32; off > 0; off >>= 1)
        lsum += __shfl_down(lsum, off);

    if ((t & 63) == 0) wsum[w] = lsum;
    __syncthreads();
    if (t == 0) {
        const float s = wsum[0] + wsum[1] + wsum[2] + wsum[3];
        atomicAdd(loss, s * (11.0f / (float)NELEM));
    }
}

extern "C" void kernel_launch(void* const* d_in, const int* in_sizes, int n_in,
                              void* d_out, int out_size, void* d_ws, size_t ws_size,
                              hipStream_t stream)
{
    const float* z     = (const float*)d_in[0];
    const float* table = (const float*)d_in[1];
    float* out  = (float*)d_out;
    float* loss = out + NELEM;

    prep_kernel<<<1, 256, 0, stream>>>(table, loss);
    vq_kernel<<<NPIX / 256, 256, 0, stream>>>(z, table, out, loss);
}